// Round 7
// baseline (2832.116 us; speedup 1.0000x reference)
//
#include <hip/hip_runtime.h>

#define B_SZ 512
#define T_SZ 256
#define D_SZ 256
#define U_SZ 512

typedef float  f32x4  __attribute__((ext_vector_type(4)));
typedef short  short8 __attribute__((ext_vector_type(8)));
typedef __bf16 bf16x8 __attribute__((ext_vector_type(8)));

static __device__ __forceinline__ unsigned short f2bf(float f) {
  unsigned u = __builtin_bit_cast(unsigned, f);
  return (unsigned short)((u + 0x7FFFu + ((u >> 16) & 1u)) >> 16);
}

static __device__ __forceinline__ f32x4 mfma_bf16(short8 a, short8 b, f32x4 c) {
  return __builtin_amdgcn_mfma_f32_16x16x32_bf16(
      __builtin_bit_cast(bf16x8, a), __builtin_bit_cast(bf16x8, b), c, 0, 0, 0);
}

static __device__ __forceinline__ float sigm(float x) {
  return 1.f / (1.f + __expf(-x));
}
static __device__ __forceinline__ float tanh_fast(float x) {
  return 1.f - 2.f / (__expf(2.f * x) + 1.f);  // safe at +/-inf
}

// ---------------- K1: transpose-cast weights into Wt[2048 cols][768 k] bf16 ----
__global__ __launch_bounds__(256) void wt_kernel(const float* __restrict__ Wx,
                                                 const float* __restrict__ Wh,
                                                 unsigned short* __restrict__ Wt) {
  __shared__ float tile[32][33];
  const int ct = blockIdx.x;       // col tile (64)
  const int kt = blockIdx.y;       // k tile (24)
  const int tx = threadIdx.x & 31;
  const int ty = threadIdx.x >> 5; // 0..7
  const int k0 = kt * 32;
#pragma unroll
  for (int q = 0; q < 4; ++q) {
    int kl = ty + q * 8;
    int kg = k0 + kl;
    float v = (kg < 256) ? Wx[(size_t)kg * 2048 + ct * 32 + tx]
                         : Wh[(size_t)(kg - 256) * 2048 + ct * 32 + tx];
    tile[kl][tx] = v;
  }
  __syncthreads();
#pragma unroll
  for (int q = 0; q < 4; ++q) {
    int cl = ty + q * 8;
    Wt[(size_t)(ct * 32 + cl) * 768 + k0 + tx] = f2bf(tile[tx][cl]);
  }
}

// ---------------- K2: persistent fused LSTM ------------------------------------
// grid = 256 WGs: 16 batch-groups (32 rows) x 16 u-strips (32 u = 128 z-cols).
// 256 threads = 4 waves = 2 m-tiles x 2 u-halves. Weights in registers (384
// regs/thread -> VGPR+AGPR unified file, 1 wave/SIMD).
// LDS (64KB): xbuf[2] double-buffer 2x16KB (x_t bf16, 32 rows x 512B) at 0;
//             hbufL 32KB (h_{t-1} bf16, 32 rows x 1024B) at 32768.
// Per step: prefetch x_{t+1} (regs) BEFORE spin -> x HBM latency hidden under
// spin+GEMM. Cross-WG sync: per-strip flag array (no RMW serialization);
// relaxed agent-scope atomics only -> no L2 invalidation, coherent at L3.
__global__ __launch_bounds__(256, 1) void lstm_kernel(
    const float* __restrict__ x, const unsigned short* __restrict__ Wt,
    const float* __restrict__ bias, unsigned short* __restrict__ hbuf,
    unsigned* __restrict__ flags, float* __restrict__ hfin) {
  extern __shared__ char smem[];
  const int tid  = threadIdx.x;
  const int lane = tid & 63;
  const int wv   = tid >> 6;            // 0..3
  const int mt   = wv & 1;              // m-tile (16 rows)
  const int uh   = wv >> 1;             // u-half within strip
  const int g    = blockIdx.x & 15;     // batch group (same-XCD strips)
  const int s    = blockIdx.x >> 4;     // u-strip 0..15
  const int col  = lane & 15;
  const int kgrp = lane >> 4;           // 0..3
  const int ug   = s * 32 + uh * 16 + col;  // global u column

  // ---- load the wave's B strip into registers: 24 kt x 4 gates ----
  short8 Bfr[96];
#pragma unroll
  for (int kt = 0; kt < 24; ++kt) {
#pragma unroll
    for (int gg = 0; gg < 4; ++gg) {
      const unsigned short* p =
          Wt + (size_t)(gg * 512 + ug) * 768 + kgrp * 8 + kt * 32;
      Bfr[kt * 4 + gg] = *(const short8*)p;
    }
  }
  float bias_g[4];
#pragma unroll
  for (int gg = 0; gg < 4; ++gg) bias_g[gg] = bias[gg * 512 + ug];

  // ---- prologue: stage x_0 into xbuf[0] ----
#pragma unroll
  for (int i = 0; i < 4; ++i) {
    int ch = tid + i * 256;
    int row = ch >> 5;
    int k0 = (ch & 31) * 8;
    const float* xp = x + ((size_t)(g * 32 + row) * T_SZ + 0) * D_SZ + k0;
    float4 a  = *(const float4*)xp;
    float4 b2 = *(const float4*)(xp + 4);
    short8 v;
    v[0] = (short)f2bf(a.x);  v[1] = (short)f2bf(a.y);
    v[2] = (short)f2bf(a.z);  v[3] = (short)f2bf(a.w);
    v[4] = (short)f2bf(b2.x); v[5] = (short)f2bf(b2.y);
    v[6] = (short)f2bf(b2.z); v[7] = (short)f2bf(b2.w);
    unsigned byte = ((unsigned)(row * 512 + k0 * 2)) ^ ((row & 7) << 4);
    *(short8*)(smem + byte) = v;
  }

  f32x4 cst = {0.f, 0.f, 0.f, 0.f};
  int p = 0;
  int par = 0;
  for (int t = 0; t < 256; ++t) {
    // ---- (1) issue x_{t+1} prefetch loads BEFORE the spin ----
    float4 xa[4], xb[4];
    if (t < 255) {
#pragma unroll
      for (int i = 0; i < 4; ++i) {
        int ch = tid + i * 256;
        int row = ch >> 5;
        int k0 = (ch & 31) * 8;
        const float* xp =
            x + ((size_t)(g * 32 + row) * T_SZ + (t + 1)) * D_SZ + k0;
        xa[i] = *(const float4*)xp;
        xb[i] = *(const float4*)(xp + 4);
      }
    }

    // ---- (2) spin: lanes 0..15 of every wave poll the 16 strip flags ----
    if (t > 0) {
      const unsigned* fb = flags + (((unsigned)(g << 8) + (t - 1)) << 4);
      if (lane < 16) {
        while (__hip_atomic_load(fb + lane, __ATOMIC_RELAXED,
                                 __HIP_MEMORY_SCOPE_AGENT) == 0u) {
        }
      }
      __builtin_amdgcn_sched_barrier(0);
    }

    // ---- (3) stage h_{t-1}: relaxed agent u64 loads -> LDS hbufL ----
    const unsigned short* hr =
        hbuf + ((size_t)p << 18) + ((size_t)(g * 32) << 9);
#pragma unroll
    for (int i = 0; i < 16; ++i) {      // 4096 u64 chunks (4 bf16 each)
      int ch = tid + i * 256;
      int row = ch >> 7;
      int c4 = ch & 127;
      const unsigned long long* hp =
          (const unsigned long long*)(hr + ((size_t)row << 9) + c4 * 4);
      unsigned long long v = __hip_atomic_load(hp, __ATOMIC_RELAXED,
                                               __HIP_MEMORY_SCOPE_AGENT);
      unsigned byte =
          (32768u + (unsigned)(row * 1024 + c4 * 8)) ^ ((row & 7) << 4);
      *(unsigned long long*)(smem + byte) = v;
    }
    __syncthreads();

    // ---- (4) convert + store x_{t+1} into xbuf[par^1] (covered by GEMM) ----
    if (t < 255) {
#pragma unroll
      for (int i = 0; i < 4; ++i) {
        int ch = tid + i * 256;
        int row = ch >> 5;
        int k0 = (ch & 31) * 8;
        short8 v;
        v[0] = (short)f2bf(xa[i].x);  v[1] = (short)f2bf(xa[i].y);
        v[2] = (short)f2bf(xa[i].z);  v[3] = (short)f2bf(xa[i].w);
        v[4] = (short)f2bf(xb[i].x);  v[5] = (short)f2bf(xb[i].y);
        v[6] = (short)f2bf(xb[i].z);  v[7] = (short)f2bf(xb[i].w);
        unsigned byte = ((unsigned)((par ^ 1) * 16384 + row * 512 + k0 * 2)) ^
                        ((row & 7) << 4);
        *(short8*)(smem + byte) = v;
      }
    }

    // ---- (5) GEMM: z[16 rows x 64 z-cols] per wave, weights from regs ----
    f32x4 acc[4];
#pragma unroll
    for (int gg = 0; gg < 4; ++gg) acc[gg] = (f32x4){0.f, 0.f, 0.f, 0.f};
    const int arow = mt * 16 + col;
    const unsigned rsw = (unsigned)((arow & 7) << 4);
#pragma unroll
    for (int kt = 0; kt < 24; ++kt) {
      unsigned byte;
      if (kt < 8)
        byte = ((unsigned)(par * 16384 + arow * 512 + kt * 64 + kgrp * 16)) ^ rsw;
      else
        byte = (32768u +
                (unsigned)(arow * 1024 + (kt - 8) * 64 + kgrp * 16)) ^ rsw;
      short8 af = *(const short8*)(smem + byte);
      acc[0] = mfma_bf16(af, Bfr[kt * 4 + 0], acc[0]);
      acc[1] = mfma_bf16(af, Bfr[kt * 4 + 1], acc[1]);
      acc[2] = mfma_bf16(af, Bfr[kt * 4 + 2], acc[2]);
      acc[3] = mfma_bf16(af, Bfr[kt * 4 + 3], acc[3]);
    }

    // ---- (6) gates + state update (lane-local) ----
#pragma unroll
    for (int j = 0; j < 4; ++j) {
      float zi = acc[0][j] + bias_g[0];
      float zf = acc[1][j] + bias_g[1];
      float zg = acc[2][j] + bias_g[2];
      float zo = acc[3][j] + bias_g[3];
      float ii = sigm(zi);
      float ff = sigm(zf);
      float gv = tanh_fast(zg);
      float oo = sigm(zo);
      float cv = ff * cst[j] + ii * gv;
      cst[j] = cv;
      float hv = oo * tanh_fast(cv);
      int brow = g * 32 + mt * 16 + kgrp * 4 + j;
      if (t == 255) {
        hfin[(size_t)brow * 512 + ug] = hv;
      } else {
        unsigned short* hp =
            hbuf + (((size_t)(p ^ 1)) << 18) + ((size_t)brow << 9) + ug;
        __hip_atomic_store(hp, f2bf(hv), __ATOMIC_RELAXED,
                           __HIP_MEMORY_SCOPE_AGENT);
      }
    }

    if (t == 255) break;

    // ---- (7) arrive: syncthreads drains vmcnt, then publish own flag ----
    __syncthreads();
    if (tid == 0) {
      __hip_atomic_store(flags + ((((unsigned)(g << 8) + t) << 4) + s), 1u,
                         __ATOMIC_RELAXED, __HIP_MEMORY_SCOPE_AGENT);
    }
    p ^= 1;
    par ^= 1;
  }
}

// ---------------- K3: MLP head + softmax ---------------------------------------
__global__ __launch_bounds__(128) void mlp_kernel(
    const float* __restrict__ hfin, const float* __restrict__ W1,
    const float* __restrict__ b1, const float* __restrict__ W2,
    const float* __restrict__ b2, float* __restrict__ out) {
  __shared__ float hrow[512];
  __shared__ float act[128];
  __shared__ float lg[10];
  const int b = blockIdx.x;
  const int tid = threadIdx.x;
#pragma unroll
  for (int i = 0; i < 4; ++i)
    hrow[tid + i * 128] = hfin[(size_t)b * 512 + tid + i * 128];
  __syncthreads();
  float s = b1[tid];
#pragma unroll 8
  for (int k = 0; k < 512; ++k) s += hrow[k] * W1[(size_t)k * 128 + tid];
  act[tid] = fmaxf(s, 0.f);
  __syncthreads();
  if (tid < 10) {
    float l = b2[tid];
#pragma unroll 8
    for (int k = 0; k < 128; ++k) l += act[k] * W2[(size_t)k * 10 + tid];
    lg[tid] = l;
  }
  __syncthreads();
  if (tid == 0) {
    float m = lg[0];
    for (int j = 1; j < 10; ++j) m = fmaxf(m, lg[j]);
    float e[10];
    float sum = 0.f;
    for (int j = 0; j < 10; ++j) {
      e[j] = expf(lg[j] - m);
      sum += e[j];
    }
    float inv = 1.f / sum;
    for (int j = 0; j < 10; ++j) out[(size_t)b * 10 + j] = e[j] * inv;
  }
}

extern "C" void kernel_launch(void* const* d_in, const int* in_sizes, int n_in,
                              void* d_out, int out_size, void* d_ws,
                              size_t ws_size, hipStream_t stream) {
  const float* x    = (const float*)d_in[0];
  const float* Wx   = (const float*)d_in[1];
  const float* Wh   = (const float*)d_in[2];
  const float* bias = (const float*)d_in[3];
  const float* W1   = (const float*)d_in[4];
  const float* b1   = (const float*)d_in[5];
  const float* W2   = (const float*)d_in[6];
  const float* b2   = (const float*)d_in[7];
  float* out = (float*)d_out;

  char* ws = (char*)d_ws;
  // layout: [0,1MB) hbuf[2][512][512] bf16 | [1MB,+256KB) flags[16][256][16] |
  //         [2MB,+3MB) Wt bf16 | [5MB,+1MB) h_final f32
  unsigned short* hbuf = (unsigned short*)ws;
  unsigned* flags      = (unsigned*)(ws + 1048576);
  unsigned short* Wt   = (unsigned short*)(ws + 2097152);
  float* hfin          = (float*)(ws + 2097152 + 3145728);

  // zero h0 (parity 0) + flags; ws is re-poisoned 0xAA before every call
  hipMemsetAsync(d_ws, 0, 1048576 + 262144, stream);

  wt_kernel<<<dim3(64, 24), 256, 0, stream>>>(Wx, Wh, Wt);

  hipFuncSetAttribute((const void*)lstm_kernel,
                      hipFuncAttributeMaxDynamicSharedMemorySize, 65536);
  lstm_kernel<<<256, 256, 65536, stream>>>(x, Wt, bias, hbuf, flags, hfin);

  mlp_kernel<<<512, 128, 0, stream>>>(hfin, W1, b1, W2, b2, out);
}